// Round 9
// baseline (153.641 us; speedup 1.0000x reference)
//
#include <hip/hip_runtime.h>
#include <hip/hip_bf16.h>

// GeometricFlow: one block per batch element, 256 threads.
// Phases: metric MLP -> christoffel (512 triples, shared-base trick) ->
//         ricci (64 pairs, shared-base trick) -> flow MLP -> out.
// All tensors are float32 (reference dtype); compute in fp32.
//
// Round-9 change: anti-stall scheduling, math identical to r8.
//  - Phase 4: explicit prefetch-distance-1 pipeline (VGPR=24 in r8 proved the
//    compiler emitted load->use back-to-back; each wave ate ~120cy LDS latency
//    per iter).
//  - Phase 5: prefetch chain-head vectors (v0,v1) one iteration ahead.
//  - g-matmul parallelized over all 256 threads (4 partials + shfl reduce);
//    was 128 serial fma + 128 global loads on one wave while 3 waited.

#define MDIM 8
#define HIDC 128   // christoffel / metric / flow hidden
#define HIDR 256   // ricci hidden

// tanh(x) ~ x * (TC0 + u*(TC1 + u*(TC2 + u*TC3))), u = x^2
#define TC0 ( 0.986156f)
#define TC1 (-0.255552f)
#define TC2 ( 0.0439642f)
#define TC3 (-0.0029314f)

typedef float f2 __attribute__((ext_vector_type(2)));

__global__ __launch_bounds__(256, 8) void geoflow_kernel(
    const float* __restrict__ points,
    const float* __restrict__ Wm1, const float* __restrict__ bm1,
    const float* __restrict__ Wm2, const float* __restrict__ bm2,
    const float* __restrict__ Wc1, const float* __restrict__ bc1,
    const float* __restrict__ Wc2, const float* __restrict__ bc2,
    const float* __restrict__ Wr1, const float* __restrict__ br1,
    const float* __restrict__ Wr2, const float* __restrict__ br2,
    const float* __restrict__ Wf1, const float* __restrict__ bf1v,
    const float* __restrict__ Wf2, const float* __restrict__ bf2v,
    float* __restrict__ outp)
{
    __shared__ float  p[MDIM];
    __shared__ float  hm[HIDC];          // metric hidden (post-relu)
    __shared__ float  g[64];             // metric tensor (row-major i*8+j)
    __shared__ float4 c4pack[64 * 3];    // christoffel: 48B per h2 {B2,WY2|WZ2,WW2|WO2,pad}
    __shared__ float  chris[512];        // chris[i*64 + j*8 + k]
    __shared__ float4 rr[128 * 6];       // ricci: 96B per h2 {B2,WG|C0,C1|C2,C3|C4,C5|C6,C7|WR2,pad}
    __shared__ float  ric[64];
    __shared__ float  flowin[2 * MDIM];
    __shared__ float  fh[HIDC];

    const int b   = blockIdx.x;
    const int tid = threadIdx.x;

    if (tid < MDIM) p[tid] = points[b * MDIM + tid];
    __syncthreads();

    // ---- phase 2: lower half -> metric hidden; upper half -> christoffel prep ----
    if (tid < 128) {
        float acc = bm1[tid];
        #pragma unroll
        for (int d = 0; d < MDIM; ++d) acc += p[d] * Wm1[d * 128 + tid];
        hm[tid] = fmaxf(acc, 0.f);
    } else {
        const int h  = tid - 128;
        const int h2 = h >> 1, q = h & 1;
        float base = bc1[h];
        #pragma unroll
        for (int d = 0; d < MDIM; ++d) base += p[d] * Wc1[d * 128 + h];
        float* cf = (float*)c4pack + h2 * 12;
        cf[0 + q] = base;
        cf[2 + q] = Wc1[8  * 128 + h];
        cf[4 + q] = Wc1[9  * 128 + h];
        cf[6 + q] = Wc1[10 * 128 + h];
        cf[8 + q] = Wc2[h];
    }
    __syncthreads();

    // ---- phase 3: ricci prep (all threads) + g-matmul (all threads, 4 partials) ----
    {
        const int h  = tid;
        const int h2 = h >> 1, q = h & 1;
        float base2 = br1[h];
        #pragma unroll
        for (int d = 0; d < MDIM; ++d) base2 += p[d] * Wr1[d * HIDR + h];
        float* rf = (float*)rr + h2 * 24;
        rf[0 + q]  = base2;
        rf[2 + q]  = Wr1[8 * HIDR + h];          // w_g
        #pragma unroll
        for (int k = 0; k < 8; ++k)
            rf[4 + 2 * k + q] = Wr1[(9 + k) * HIDR + h];  // w_chris_k
        rf[20 + q] = Wr2[h];
    }
    {
        // g[o] = bm2[o] + sum_h hm[h]*Wm2[h*64+o]; o = tid>>2, s = tid&3
        const int o = tid >> 2, s = tid & 3;
        float acc = 0.f;
        const int h0 = s * 32;
        #pragma unroll 8
        for (int hh = 0; hh < 32; ++hh) {
            const int h = h0 + hh;
            acc += hm[h] * Wm2[h * 64 + o];
        }
        acc += __shfl_xor(acc, 1);
        acc += __shfl_xor(acc, 2);
        if (s == 0) g[o] = acc + bm2[o];
    }
    __syncthreads();

    // ---- phase 4: christoffel, 2 triples/thread, (h,h+1) packed, prefetch-1 ----
    // t0 = tid, t1 = tid + 256  ->  i1 = i0 + 4, same j,k  ->  shared partial.
    {
        const int t0 = tid;
        const int i0 = t0 >> 6, j0 = (t0 >> 3) & 7, k0 = t0 & 7;
        const int i1 = i0 + 4;
        const float gij0 = g[i0 * 8 + j0];
        const float gij1 = g[i1 * 8 + j0];
        const float gjk  = g[j0 * 8 + k0];
        const float gki0 = g[k0 * 8 + i0];
        const float gki1 = g[k0 * 8 + i1];

        const f2 GJK  = {gjk,  gjk};
        const f2 GIJ0 = {gij0, gij0};
        const f2 GIJ1 = {gij1, gij1};
        const f2 GKI0 = {gki0, gki0};
        const f2 GKI1 = {gki1, gki1};
        const f2 C3 = {TC3, TC3}, C2v = {TC2, TC2};
        const f2 C1v = {TC1, TC1}, C0v = {TC0, TC0};

        f2 a0 = {0.f, 0.f}, a1 = {0.f, 0.f};
        float4 cq0 = c4pack[0];
        float4 cq1 = c4pack[1];
        f2 cwo = ((const f2*)c4pack)[4];
        #pragma unroll 4
        for (int h2 = 0; h2 < HIDC / 2; ++h2) {
            const int nn = (h2 + 1) & (HIDC / 2 - 1);
            const float4 nq0 = c4pack[nn * 3 + 0];      // prefetch next record
            const float4 nq1 = c4pack[nn * 3 + 1];
            const f2 nwo = ((const f2*)c4pack)[nn * 6 + 4];
            const f2 B  = {cq0.x, cq0.y};
            const f2 WY = {cq0.z, cq0.w};
            const f2 WZ = {cq1.x, cq1.y};
            const f2 WW = {cq1.z, cq1.w};
            const f2 S  = __builtin_elementwise_fma(GJK, WZ, B);
            const f2 X0 = __builtin_elementwise_fma(
                              GIJ0, WY, __builtin_elementwise_fma(GKI0, WW, S));
            const f2 X1 = __builtin_elementwise_fma(
                              GIJ1, WY, __builtin_elementwise_fma(GKI1, WW, S));
            const f2 U0 = X0 * X0;
            const f2 U1 = X1 * X1;
            f2 T0 = __builtin_elementwise_fma(U0, C3, C2v);
            T0 = __builtin_elementwise_fma(U0, T0, C1v);
            T0 = __builtin_elementwise_fma(U0, T0, C0v);
            f2 T1 = __builtin_elementwise_fma(U1, C3, C2v);
            T1 = __builtin_elementwise_fma(U1, T1, C1v);
            T1 = __builtin_elementwise_fma(U1, T1, C0v);
            a0 = __builtin_elementwise_fma(cwo, X0 * T0, a0);
            a1 = __builtin_elementwise_fma(cwo, X1 * T1, a1);
            cq0 = nq0; cq1 = nq1; cwo = nwo;
        }
        const float cb = bc2[0];
        chris[t0]       = a0.x + a0.y + cb;
        chris[t0 + 256] = a1.x + a1.y + cb;
    }
    __syncthreads();

    // ---- phase 5: ricci, 4 threads/pair, f2-packed (h,h+1), prefetch chain head ----
    {
        const int pair = tid >> 2;   // i*8 + j
        const int part = tid & 3;
        const float gij = g[pair];
        const f2 GIJ = {gij, gij};
        f2 CH[8];
        #pragma unroll
        for (int k = 0; k < 8; ++k) {
            const float c = chris[pair * 8 + k];
            CH[k] = (f2){c, c};
        }
        f2 acc = {0.f, 0.f};
        float4 cv0 = rr[part * 6 + 0];
        float4 cv1 = rr[part * 6 + 1];
        #pragma unroll 4
        for (int idx = 0; idx < 32; ++idx) {
            const int cur = (idx << 2) | part;             // parts hit disjoint bank quads
            const int nxt = (((idx + 1) & 31) << 2) | part;
            const float4 nv0 = rr[nxt * 6 + 0];            // prefetch chain head
            const float4 nv1 = rr[nxt * 6 + 1];
            const float4 v2 = rr[cur * 6 + 2];
            const float4 v3 = rr[cur * 6 + 3];
            const float4 v4 = rr[cur * 6 + 4];
            const f2 WR2 = ((const f2*)rr)[cur * 12 + 10];
            f2 x = (f2){cv0.x, cv0.y};                                   // base2
            x = __builtin_elementwise_fma(GIJ,   (f2){cv0.z, cv0.w}, x);
            x = __builtin_elementwise_fma(CH[0], (f2){cv1.x, cv1.y}, x);
            x = __builtin_elementwise_fma(CH[1], (f2){cv1.z, cv1.w}, x);
            x = __builtin_elementwise_fma(CH[2], (f2){v2.x, v2.y}, x);
            x = __builtin_elementwise_fma(CH[3], (f2){v2.z, v2.w}, x);
            x = __builtin_elementwise_fma(CH[4], (f2){v3.x, v3.y}, x);
            x = __builtin_elementwise_fma(CH[5], (f2){v3.z, v3.w}, x);
            x = __builtin_elementwise_fma(CH[6], (f2){v4.x, v4.y}, x);
            x = __builtin_elementwise_fma(CH[7], (f2){v4.z, v4.w}, x);
            x = __builtin_elementwise_max(x, (f2){0.f, 0.f});
            acc = __builtin_elementwise_fma(x, WR2, acc);
            cv0 = nv0; cv1 = nv1;
        }
        float s = acc.x + acc.y;
        s += __shfl_xor(s, 1);
        s += __shfl_xor(s, 2);
        if (part == 0) ric[pair] = s + br2[0];
    }
    __syncthreads();

    // ---- phase 6: ric . p, build flow input ----
    if (tid < MDIM) {
        float rp = 0.f;
        #pragma unroll
        for (int j = 0; j < MDIM; ++j) rp += ric[tid * 8 + j] * p[j];
        flowin[tid]        = p[tid];
        flowin[MDIM + tid] = rp;
    }
    __syncthreads();

    // ---- phase 7: flow hidden ----
    if (tid < 128) {
        float acc = bf1v[tid];
        #pragma unroll
        for (int d = 0; d < 2 * MDIM; ++d) acc += flowin[d] * Wf1[d * 128 + tid];
        fh[tid] = fmaxf(acc, 0.f);
    }
    __syncthreads();

    // ---- phase 8: flow out + final update ----
    if (tid < MDIM) {
        float acc = bf2v[tid];
        for (int h = 0; h < 128; ++h) acc += fh[h] * Wf2[h * 8 + tid];
        outp[b * MDIM + tid] = p[tid] + 0.01f * acc;
    }
}

extern "C" void kernel_launch(void* const* d_in, const int* in_sizes, int n_in,
                              void* d_out, int out_size, void* d_ws, size_t ws_size,
                              hipStream_t stream) {
    const float* points = (const float*)d_in[0];
    const float* Wm1 = (const float*)d_in[1];
    const float* bm1 = (const float*)d_in[2];
    const float* Wm2 = (const float*)d_in[3];
    const float* bm2 = (const float*)d_in[4];
    const float* Wc1 = (const float*)d_in[5];
    const float* bc1 = (const float*)d_in[6];
    const float* Wc2 = (const float*)d_in[7];
    const float* bc2 = (const float*)d_in[8];
    const float* Wr1 = (const float*)d_in[9];
    const float* br1 = (const float*)d_in[10];
    const float* Wr2 = (const float*)d_in[11];
    const float* br2 = (const float*)d_in[12];
    const float* Wf1 = (const float*)d_in[13];
    const float* bf1v = (const float*)d_in[14];
    const float* Wf2 = (const float*)d_in[15];
    const float* bf2v = (const float*)d_in[16];
    float* outp = (float*)d_out;

    const int BATCH = in_sizes[0] / MDIM;   // 4096
    geoflow_kernel<<<BATCH, 256, 0, stream>>>(
        points, Wm1, bm1, Wm2, bm2, Wc1, bc1, Wc2, bc2,
        Wr1, br1, Wr2, br2, Wf1, bf1v, Wf2, bf2v, outp);
}